// Round 1
// baseline (274.040 us; speedup 1.0000x reference)
//
#include <hip/hip_runtime.h>

#define TD 16
#define ZD 16
#define YD 16
#define XH 8
#define DD 12
#define NSITES (TD*ZD*YD*XH)      // 32768
#define SPB 16                    // sites per block
#define THREADS (SPB*DD)          // 192
#define DIAG 4.5f
#define VSTRIDE 100               // 96 used + pad -> site stride % 32 == 4 banks

__global__ __launch_bounds__(THREADS) void hop_kernel(
    const float* __restrict__ psi_re, const float* __restrict__ psi_im,
    const float* __restrict__ K_fwd_re, const float* __restrict__ K_fwd_im,
    const float* __restrict__ K_bwd_re, const float* __restrict__ K_bwd_im,
    float* __restrict__ out_re, float* __restrict__ out_im)
{
    __shared__ float vre[SPB][VSTRIDE];
    __shared__ float vim[SPB][VSTRIDE];
    __shared__ int   nidx[SPB][8];

    const int tid   = threadIdx.x;
    const int site0 = blockIdx.x * SPB;

    // ---- phase 0: neighbor site indices (16 sites x 8 (mu,dir) combos) ----
    if (tid < SPB * 8) {
        const int s = tid >> 3, c = tid & 7;
        const int sg = site0 + s;
        const int x = sg & 7, y = (sg >> 3) & 15, z = (sg >> 7) & 15, t = (sg >> 11) & 15;
        const int r = (t + z + y) & 1;           // OUT_PARITY = 0
        int nt = t, nz = z, ny = y, nx = x;
        switch (c) {
            case 0: nt = (t + 1)  & 15; break;   // T fwd
            case 1: nt = (t + 15) & 15; break;   // T bwd
            case 2: nz = (z + 1)  & 15; break;   // Z fwd
            case 3: nz = (z + 15) & 15; break;   // Z bwd
            case 4: ny = (y + 1)  & 15; break;   // Y fwd
            case 5: ny = (y + 15) & 15; break;   // Y bwd
            case 6: if (r == 1) nx = (x + 1) & 7; break;  // X fwd: mask_f = (r==1)
            case 7: if (r == 0) nx = (x + 7) & 7; break;  // X bwd: mask_b = (r==0)
        }
        nidx[s][c] = ((nt * 16 + nz) * 16 + ny) * 8 + nx;
    }
    __syncthreads();

    // ---- phase 1: stage shifted psi vectors into LDS ----
    // 16 sites x 8 combos x 12 components = 1536 (re,im) pairs
    for (int e = tid; e < SPB * 8 * DD; e += THREADS) {
        const int j  = e % 12;
        const int sc = e / 12;
        const int s  = sc >> 3, c = sc & 7;
        const int n  = nidx[s][c];
        vre[s][c * 12 + j] = psi_re[n * 12 + j];
        vim[s][c * 12 + j] = psi_im[n * 12 + j];
    }
    __syncthreads();

    // ---- phase 2: per-(site,row) complex dot products over streamed K ----
    const int s    = tid / 12;       // local site 0..15
    const int i    = tid - s * 12;   // output row 0..11
    const int site = site0 + s;

    const float pr_c = psi_re[site * 12 + i];   // coalesced: index = block*192 + tid
    const float pi_c = psi_im[site * 12 + i];
    float o_re = DIAG * pr_c;
    float o_im = DIAG * pi_c;

    #pragma unroll 2
    for (int c = 0; c < 8; ++c) {
        const int mu = c >> 1;
        const float* __restrict__ Kr_arr = (c & 1) ? K_bwd_re : K_fwd_re;
        const float* __restrict__ Ki_arr = (c & 1) ? K_bwd_im : K_fwd_im;
        const int off = (mu * NSITES + site) * 144 + i * 12;   // 16B-aligned (48B units)
        const float4* Kr4 = (const float4*)(Kr_arr + off);
        const float4* Ki4 = (const float4*)(Ki_arr + off);
        const float4 a0 = Kr4[0], a1 = Kr4[1], a2 = Kr4[2];
        const float4 b0 = Ki4[0], b1 = Ki4[1], b2 = Ki4[2];
        const float kr[12] = {a0.x,a0.y,a0.z,a0.w, a1.x,a1.y,a1.z,a1.w, a2.x,a2.y,a2.z,a2.w};
        const float ki[12] = {b0.x,b0.y,b0.z,b0.w, b1.x,b1.y,b1.z,b1.w, b2.x,b2.y,b2.z,b2.w};
        const float* __restrict__ vr = &vre[s][c * 12];
        const float* __restrict__ vi = &vim[s][c * 12];
        float sr = 0.f, si = 0.f;
        #pragma unroll
        for (int j = 0; j < 12; ++j) {
            const float krj = kr[j], kij = ki[j];
            const float vrj = vr[j], vij = vi[j];   // 12 same-site lanes broadcast
            sr += krj * vrj - kij * vij;
            si += krj * vij + kij * vrj;
        }
        o_re -= 0.5f * sr;
        o_im -= 0.5f * si;
    }

    out_re[site * 12 + i] = o_re;   // index = block*192 + tid: fully coalesced
    out_im[site * 12 + i] = o_im;
}

extern "C" void kernel_launch(void* const* d_in, const int* in_sizes, int n_in,
                              void* d_out, int out_size, void* d_ws, size_t ws_size,
                              hipStream_t stream) {
    const float* psi_re   = (const float*)d_in[0];
    const float* psi_im   = (const float*)d_in[1];
    const float* K_fwd_re = (const float*)d_in[2];
    const float* K_fwd_im = (const float*)d_in[3];
    const float* K_bwd_re = (const float*)d_in[4];
    const float* K_bwd_im = (const float*)d_in[5];
    float* out_re = (float*)d_out;
    float* out_im = out_re + (out_size / 2);    // 393216 = NSITES * 12

    hop_kernel<<<NSITES / SPB, THREADS, 0, stream>>>(
        psi_re, psi_im, K_fwd_re, K_fwd_im, K_bwd_re, K_bwd_im, out_re, out_im);
}